// Round 5
// baseline (370.160 us; speedup 1.0000x reference)
//
#include <hip/hip_runtime.h>
#include <hip/hip_bf16.h>

// Problem constants
#define SB 2048
#define DB 512
#define HB 8
#define DKB 64
#define DFB 2048
#define BATCH 4

typedef __attribute__((ext_vector_type(8))) short bf16x8;
typedef __attribute__((ext_vector_type(4))) float f32x4;
typedef __attribute__((ext_vector_type(2))) float f32x2;
typedef __attribute__((ext_vector_type(2))) unsigned u32x2;
typedef __attribute__((ext_vector_type(4))) short s16x4;

static __device__ __forceinline__ short f2bf(float x) {
  union { float f; unsigned u; } v; v.f = x;
  unsigned r = (v.u + 0x7fffu + ((v.u >> 16) & 1u)) >> 16;
  return (short)(unsigned short)r;
}

static __device__ __forceinline__ unsigned pack2bf(float a, float b) {
  return (unsigned)(unsigned short)f2bf(a) | ((unsigned)(unsigned short)f2bf(b) << 16);
}

static __device__ __forceinline__ f32x4 mfma16(bf16x8 a, bf16x8 b, f32x4 c) {
  return __builtin_amdgcn_mfma_f32_16x16x32_bf16(a, b, c, 0, 0, 0);
}

// async global->LDS, 16B per lane; LDS dest is wave-uniform base + lane*16
static __device__ __forceinline__ void gload_lds16(const short* g, short* l) {
  __builtin_amdgcn_global_load_lds(
      (const __attribute__((address_space(1))) unsigned*)g,
      (__attribute__((address_space(3))) unsigned*)l, 16, 0, 0);
}

// ---------------- weight prep ----------------
__global__ __launch_bounds__(256) void conv_kernel(const float* __restrict__ src,
                                                   short* __restrict__ dst, int n) {
  int i = blockIdx.x * 256 + threadIdx.x;
  if (i < n) dst[i] = f2bf(src[i]);
}

// dst[n*K + k] = src[k*N + n] * scale   (produce B^T, bf16)
__global__ __launch_bounds__(256) void tconv_kernel(const float* __restrict__ src,
                                                    short* __restrict__ dst,
                                                    int K, int N, float scale) {
  int i = blockIdx.x * 256 + threadIdx.x;
  if (i >= K * N) return;
  int n = i / K, k = i - n * K;
  dst[i] = f2bf(src[(size_t)k * N + n] * scale);
}

// ---------------- layernorm: one wave per 512-elem row ----------------
__global__ __launch_bounds__(256) void ln_kernel(const float* __restrict__ in,
                                                 const float* __restrict__ g,
                                                 const float* __restrict__ bb,
                                                 short* __restrict__ out) {
  int w = threadIdx.x >> 6, l = threadIdx.x & 63;
  size_t row = (size_t)blockIdx.x * 4 + w;
  const float* xr = in + row * DB;
  f32x4 v0 = *(const f32x4*)(xr + l * 8);
  f32x4 v1 = *(const f32x4*)(xr + l * 8 + 4);
  float s = (v0[0] + v0[1]) + (v0[2] + v0[3]) + (v1[0] + v1[1]) + (v1[2] + v1[3]);
  float s2 = (v0[0] * v0[0] + v0[1] * v0[1]) + (v0[2] * v0[2] + v0[3] * v0[3]) +
             (v1[0] * v1[0] + v1[1] * v1[1]) + (v1[2] * v1[2] + v1[3] * v1[3]);
#pragma unroll
  for (int off = 1; off < 64; off <<= 1) {
    s += __shfl_xor(s, off, 64);
    s2 += __shfl_xor(s2, off, 64);
  }
  float mean = s * (1.f / DB);
  float var = s2 * (1.f / DB) - mean * mean;
  float rstd = rsqrtf(var + 1e-6f);
  f32x4 g0 = *(const f32x4*)(g + l * 8);
  f32x4 g1 = *(const f32x4*)(g + l * 8 + 4);
  f32x4 b0 = *(const f32x4*)(bb + l * 8);
  f32x4 b1 = *(const f32x4*)(bb + l * 8 + 4);
  bf16x8 ov;
#pragma unroll
  for (int e = 0; e < 4; ++e) ov[e] = f2bf((v0[e] - mean) * rstd * g0[e] + b0[e]);
#pragma unroll
  for (int e = 0; e < 4; ++e) ov[4 + e] = f2bf((v1[e] - mean) * rstd * g1[e] + b1[e]);
  *(bf16x8*)(out + row * DB + l * 8) = ov;
}

// ---------------- GEMM: C[M,N] = A[M,K]bf16 * BT[N,K]bf16 ----------------
// m97 structure: 128x128 tile, BK=32, 4 waves (2x2), global_load_lds staging.
template <int KD, int EPI>
__global__ __launch_bounds__(256) void gemm_kernel(
    const short* __restrict__ A, const short* __restrict__ BT,
    const float* __restrict__ bias, const float* __restrict__ resid,
    short* __restrict__ o0, short* __restrict__ o1, short* __restrict__ o2,
    float* __restrict__ of) {
  __shared__ short As[4096];  // 128 rows x 32 k
  __shared__ short Bs[4096];
  int tid = threadIdx.x;
  int l = tid & 63, w = tid >> 6;
  int wr = w >> 1, wc = w & 1;
  int lr = l & 15, lq = l >> 4;
  int row0 = blockIdx.y * 128;
  int col0 = blockIdx.x * 128;

  f32x4 acc[4][4];
#pragma unroll
  for (int a = 0; a < 4; ++a)
#pragma unroll
    for (int b = 0; b < 4; ++b) acc[a][b] = (f32x4){0.f, 0.f, 0.f, 0.f};

  const short* gA = A + (size_t)(row0 + (tid >> 2)) * KD + (tid & 3) * 8;
  const short* gB = BT + (size_t)(col0 + (tid >> 2)) * KD + (tid & 3) * 8;
  const size_t step64 = (size_t)64 * KD;
  short* lA = As + w * 512;
  short* lB = Bs + w * 512;

  for (int k0 = 0; k0 < KD; k0 += 32) {
    gload_lds16(gA + k0, lA);
    gload_lds16(gA + step64 + k0, lA + 2048);
    gload_lds16(gB + k0, lB);
    gload_lds16(gB + step64 + k0, lB + 2048);
    __syncthreads();
    bf16x8 af[4], bfv[4];
#pragma unroll
    for (int a = 0; a < 4; ++a)
      af[a] = *(const bf16x8*)(As + (wr * 64 + a * 16 + lr) * 32 + lq * 8);
#pragma unroll
    for (int b = 0; b < 4; ++b)
      bfv[b] = *(const bf16x8*)(Bs + (wc * 64 + b * 16 + lr) * 32 + lq * 8);
#pragma unroll
    for (int a = 0; a < 4; ++a)
#pragma unroll
      for (int b = 0; b < 4; ++b)
        acc[a][b] = mfma16(af[a], bfv[b], acc[a][b]);
    __syncthreads();
  }

#pragma unroll
  for (int a = 0; a < 4; ++a)
#pragma unroll
    for (int b = 0; b < 4; ++b)
#pragma unroll
      for (int r = 0; r < 4; ++r) {
        size_t row = (size_t)row0 + wr * 64 + a * 16 + lq * 4 + r;
        size_t col = (size_t)col0 + wc * 64 + b * 16 + lr;
        float val = acc[a][b][r];
        if (EPI == 0) {
          int sect = (int)(col >> 9);
          int hh = (int)((col >> 6) & 7);
          int d = (int)(col & 63);
          size_t b_ = row >> 11, s_ = row & 2047;
          size_t bh = b_ * HB + hh;
          short bv = f2bf(val);
          if (sect == 0) o0[(bh * SB + s_) * DKB + d] = bv;
          else if (sect == 1) o1[(bh * SB + s_) * DKB + d] = bv;
          else o2[(bh * DKB + d) * SB + s_] = bv;  // V transposed
        } else if (EPI == 1) {
          of[row * DB + col] = resid[row * DB + col] + val + bias[col];
        } else {
          float tv = val + bias[col];
          o0[row * DFB + col] = f2bf(tv > 0.f ? tv : 0.f);
        }
      }
}

static __device__ __forceinline__ void attn_out(const f32x4* acc, float lrun,
                                                short* out, int bh, int i0,
                                                int lr, int lq) {
  float inv = 1.f / lrun;
  int b_ = bh >> 3, hd = bh & 7;
  short* orow = out + ((size_t)(b_ * SB + i0 + lr) * DB + hd * 64);
#pragma unroll
  for (int dt = 0; dt < 4; ++dt) {
    s16x4 pkv;
#pragma unroll
    for (int r = 0; r < 4; ++r) pkv[r] = f2bf(acc[dt][r] * inv);
    *(s16x4*)(orow + dt * 16 + lq * 4) = pkv;
  }
}

// ---------------- fused causal attention with relative positions ----------
// Single-chain waves (4096 total -> 16 waves/CU), defer-max softmax:
// no cross-lane reduction on the common path; per-lane sum reduced once at end.
// Block waves handle qt in {g, 63-g, 64+g, 127-g} -> constant per-block work.
// XCD swizzle: bid&7 selects XCD; 4 heads per XCD -> L2-resident K/V/E.
__global__ __launch_bounds__(256, 4) void attn_kernel(
    const short* __restrict__ Q, const short* __restrict__ Kb,
    const short* __restrict__ VT, const short* __restrict__ Eb,
    short* __restrict__ out) {
  __shared__ float band[4][16][86];
  __shared__ short Pl[4][1024];
  int tid = threadIdx.x;
  int l = tid & 63, w = tid >> 6;
  int lr = l & 15, lq = l >> 4;
  int bid = blockIdx.x;                  // 1024 blocks
  int slot = bid >> 3;                   // [0,128)
  int bh = (bid & 7) * 4 + (slot >> 5);  // 4 heads per XCD slot
  int g = slot & 31;
  int qt = (w == 0) ? g : (w == 1) ? 63 - g : (w == 2) ? 64 + g : 127 - g;
  int i0 = qt << 4;
  const short* Qh = Q + (size_t)bh * SB * DKB;
  const short* Kh = Kb + (size_t)bh * SB * DKB;
  const short* Vh = VT + (size_t)bh * DKB * SB;
  const short* Eh = Eb + (size_t)(bh & 7) * SB * DKB;

  bf16x8 qf0 = *(const bf16x8*)(Qh + (size_t)(i0 + lr) * DKB + lq * 8);
  bf16x8 qf1 = *(const bf16x8*)(Qh + (size_t)(i0 + lr) * DKB + 32 + lq * 8);

  const f32x4 zz = {0.f, 0.f, 0.f, 0.f};
  f32x4 acco[4];
#pragma unroll
  for (int dt = 0; dt < 4; ++dt) acco[dt] = zz;
  float mrun = -1e30f;
  float lsum = 0.f;  // per-lane partial softmax denominator (reduced at end)
  float* bd = &band[w][0][0];
  short* pb = &Pl[w][0];

  for (int j0 = 0; j0 <= i0 + 15; j0 += 64) {
    // ---- QK^T swapped: lane holds S[q=lr][n = hh*16+lq*4+r] ----
    f32x4 sc[4];
#pragma unroll
    for (int hh = 0; hh < 4; ++hh) {
      const short* kp = Kh + (size_t)(j0 + hh * 16 + lr) * DKB + lq * 8;
      sc[hh] = mfma16(*(const bf16x8*)kp, qf0, zz);
      sc[hh] = mfma16(*(const bf16x8*)(kp + 32), qf1, sc[hh]);
    }
    // ---- rel band: R[q=lr][t = nt*16+lq*4+r], t in [0,80) ----
    int rbase = SB - 16 - i0 + j0;
#pragma unroll
    for (int nt = 0; nt < 5; ++nt) {
      int er = rbase + nt * 16 + lr;
      er = er < SB ? er : SB - 1;
      const short* ep = Eh + (size_t)er * DKB + lq * 8;
      f32x4 rr = mfma16(*(const bf16x8*)ep, qf0, zz);
      rr = mfma16(*(const bf16x8*)(ep + 32), qf1, rr);
      int bi = lr * 86 + nt * 16 + lq * 4;
      *(f32x2*)(bd + bi) = (f32x2){rr[0], rr[1]};
      *(f32x2*)(bd + bi + 2) = (f32x2){rr[2], rr[3]};
    }
    // ---- V kc=0 prefetch (latency hides under softmax) ----
    bf16x8 vf0[4];
#pragma unroll
    for (int dt = 0; dt < 4; ++dt)
      vf0[dt] = *(const bf16x8*)(Vh + (size_t)(dt * 16 + lr) * SB + j0 + lq * 8);
    // ---- scores (band gather) + per-lane max tree ----
    float s[4][4];
    int thr = i0 + lr - j0;
    if (j0 + 63 > i0) {
#pragma unroll
      for (int hh = 0; hh < 4; ++hh)
#pragma unroll
        for (int r = 0; r < 4; ++r) {
          int n = hh * 16 + lq * 4 + r;
          float v = sc[hh][r] + bd[lr * 86 + (n - lr + 15)];
          s[hh][r] = (n <= thr) ? v : -1e30f;
        }
    } else {
#pragma unroll
      for (int hh = 0; hh < 4; ++hh)
#pragma unroll
        for (int r = 0; r < 4; ++r)
          s[hh][r] = sc[hh][r] + bd[lr * 86 + (hh * 16 + lq * 4 + r - lr + 15)];
    }
    float m01 = fmaxf(fmaxf(s[0][0], s[0][1]), fmaxf(s[0][2], s[0][3]));
    float m11 = fmaxf(fmaxf(s[1][0], s[1][1]), fmaxf(s[1][2], s[1][3]));
    float m21 = fmaxf(fmaxf(s[2][0], s[2][1]), fmaxf(s[2][2], s[2][3]));
    float m31 = fmaxf(fmaxf(s[3][0], s[3][1]), fmaxf(s[3][2], s[3][3]));
    float tm = fmaxf(fmaxf(m01, m11), fmaxf(m21, m31));
    // ---- defer-max: only rescale when some lane exceeds mrun+8 ----
    if (!__all(tm <= mrun + 8.f)) {
      float tr = fmaxf(tm, __shfl_xor(tm, 16, 64));
      tr = fmaxf(tr, __shfl_xor(tr, 32, 64));
      float mnew = fmaxf(mrun, tr);
      float corr = __expf(mrun - mnew);
      mrun = mnew;
      lsum *= corr;
#pragma unroll
      for (int dt = 0; dt < 4; ++dt) acco[dt] *= corr;
    }
    // ---- exp, pack, per-lane sum, P store ----
#pragma unroll
    for (int hh = 0; hh < 4; ++hh) {
      float p0 = __expf(s[hh][0] - mrun);
      float p1 = __expf(s[hh][1] - mrun);
      float p2 = __expf(s[hh][2] - mrun);
      float p3 = __expf(s[hh][3] - mrun);
      lsum += (p0 + p1) + (p2 + p3);
      u32x2 pk = {pack2bf(p0, p1), pack2bf(p2, p3)};
      int byteoff = lr * 128 + ((((hh << 1) | (lq >> 1)) ^ (lr & 7)) << 4) + ((lq & 1) << 3);
      *(u32x2*)((char*)pb + byteoff) = pk;
    }
    // ---- V kc=1 loads ----
    bf16x8 vf1[4];
#pragma unroll
    for (int dt = 0; dt < 4; ++dt)
      vf1[dt] = *(const bf16x8*)(Vh + (size_t)(dt * 16 + lr) * SB + j0 + 32 + lq * 8);
    // ---- PV: O^T[d][q] += V^T[d][n] * P^T[n][q] ----
    {
      bf16x8 pf0 = *(const bf16x8*)((char*)pb + lr * 128 + ((lq ^ (lr & 7)) << 4));
      __builtin_amdgcn_s_setprio(1);
#pragma unroll
      for (int dt = 0; dt < 4; ++dt) acco[dt] = mfma16(vf0[dt], pf0, acco[dt]);
      __builtin_amdgcn_s_setprio(0);
      bf16x8 pf1 = *(const bf16x8*)((char*)pb + lr * 128 + (((4 | lq) ^ (lr & 7)) << 4));
      __builtin_amdgcn_s_setprio(1);
#pragma unroll
      for (int dt = 0; dt < 4; ++dt) acco[dt] = mfma16(vf1[dt], pf1, acco[dt]);
      __builtin_amdgcn_s_setprio(0);
    }
  }
  // ---- epilogue: reduce per-lane sums across the 4 lq lanes once ----
  float lt = lsum + __shfl_xor(lsum, 16, 64);
  lt += __shfl_xor(lt, 32, 64);
  attn_out(acco, lt, out, bh, i0, lr, lq);
}

// ---------------- host ----------------
extern "C" void kernel_launch(void* const* d_in, const int* in_sizes, int n_in,
                              void* d_out, int out_size, void* d_ws, size_t ws_size,
                              hipStream_t stream) {
  const float* x    = (const float*)d_in[0];
  const float* wq   = (const float*)d_in[2];
  const float* wk   = (const float*)d_in[3];
  const float* wv   = (const float*)d_in[4];
  const float* w0   = (const float*)d_in[5];
  const float* b0   = (const float*)d_in[6];
  const float* rel  = (const float*)d_in[7];
  const float* ln1g = (const float*)d_in[8];
  const float* ln1b = (const float*)d_in[9];
  const float* ln2g = (const float*)d_in[10];
  const float* ln2b = (const float*)d_in[11];
  const float* fw1  = (const float*)d_in[12];
  const float* fb1  = (const float*)d_in[13];
  const float* fw2  = (const float*)d_in[14];
  const float* fb2  = (const float*)d_in[15];
  float* outp = (float*)d_out;

  char* ws = (char*)d_ws;
  size_t off = 0;
  auto alloc = [&](size_t bytes) {
    char* p = ws + off;
    off += (bytes + 255) & ~(size_t)255;
    return p;
  };
  short* wqkvT = (short*)alloc((size_t)1536 * 512 * 2);
  short* w0T   = (short*)alloc((size_t)512 * 512 * 2);
  short* fw1T  = (short*)alloc((size_t)2048 * 512 * 2);
  short* fw2T  = (short*)alloc((size_t)512 * 2048 * 2);
  short* relb  = (short*)alloc((size_t)8 * 2048 * 64 * 2);
  short* hbuf  = (short*)alloc((size_t)8192 * 512 * 2);
  short* Qb    = (short*)alloc((size_t)8192 * 512 * 2);
  short* Kbf   = (short*)alloc((size_t)8192 * 512 * 2);
  short* VTb   = (short*)alloc((size_t)8192 * 512 * 2);
  short* attnb = (short*)alloc((size_t)8192 * 512 * 2);
  float* x2    = (float*)alloc((size_t)8192 * 512 * 4);
  short* ff1 = hbuf;
  short* h2  = attnb;

  dim3 blk(256);
  conv_kernel<<<(8 * 2048 * 64 + 255) / 256, blk, 0, stream>>>(rel, relb, 8 * 2048 * 64);
  tconv_kernel<<<(512 * 512 + 255) / 256, blk, 0, stream>>>(wq, wqkvT, 512, 512, 1.f);
  tconv_kernel<<<(512 * 512 + 255) / 256, blk, 0, stream>>>(wk, wqkvT + 512 * 512, 512, 512, 0.125f);
  tconv_kernel<<<(512 * 512 + 255) / 256, blk, 0, stream>>>(wv, wqkvT + 1024 * 512, 512, 512, 1.f);
  tconv_kernel<<<(512 * 512 + 255) / 256, blk, 0, stream>>>(w0, w0T, 512, 512, 1.f);
  tconv_kernel<<<(512 * 2048 + 255) / 256, blk, 0, stream>>>(fw1, fw1T, 512, 2048, 1.f);
  tconv_kernel<<<(512 * 2048 + 255) / 256, blk, 0, stream>>>(fw2, fw2T, 2048, 512, 1.f);

  ln_kernel<<<2048, blk, 0, stream>>>(x, ln1g, ln1b, hbuf);
  gemm_kernel<512, 0><<<dim3(12, 64), blk, 0, stream>>>(hbuf, wqkvT, nullptr, nullptr,
                                                        Qb, Kbf, VTb, nullptr);
  attn_kernel<<<1024, blk, 0, stream>>>(Qb, Kbf, VTb, relb, attnb);
  gemm_kernel<512, 1><<<dim3(4, 64), blk, 0, stream>>>(attnb, w0T, b0, x,
                                                       nullptr, nullptr, nullptr, x2);
  ln_kernel<<<2048, blk, 0, stream>>>(x2, ln2g, ln2b, h2);
  gemm_kernel<512, 2><<<dim3(16, 64), blk, 0, stream>>>(h2, fw1T, fb1, nullptr,
                                                        ff1, nullptr, nullptr, nullptr);
  gemm_kernel<2048, 1><<<dim3(4, 64), blk, 0, stream>>>(ff1, fw2T, fb2, x2,
                                                        nullptr, nullptr, nullptr, outp);
}